// Round 1
// baseline (329.135 us; speedup 1.0000x reference)
//
#include <hip/hip_runtime.h>

// Problem constants (fixed by setup_inputs)
constexpr int B  = 2, T = 2, C = 6, Cr = 64, Hp = 32, Wp = 88;
constexpr int H  = 256, W = 704;
constexpr int HB = 200, WB = 200;
constexpr int NB   = B * T * C;       // 24 camera-slices
constexpr int BT   = B * T;           // 4
constexpr int P    = Hp * Wp;         // 2816 points per slice (= 11*256)
constexpr int NBIN = HB * WB;         // 40000 bins

constexpr float X_MIN = -50.f, X_MAX = 50.f;
constexpr float Y_MIN = -50.f, Y_MAX = 50.f;
// rx = ry = 100/200 = 0.5 -> multiply by 2.0 (exact)

constexpr size_t NUM_ELEMS = (size_t)BT * NBIN * Cr;   // 10,240,000 floats
constexpr size_t CNT_ELEMS = (size_t)NB * NBIN;        //    960,000 ints
constexpr size_t NUM_BYTES = NUM_ELEMS * 4;
constexpr size_t CNT_BYTES = CNT_ELEMS * 4;

// ---------------------------------------------------------------------------
// Phase A: per-point geometry -> bin index (or -1), per-camera bin counts
// grid = (P/256, NB), block = 256  (P == 11*256 exactly, no bounds check)
// ---------------------------------------------------------------------------
__global__ void geom_kernel(const float* __restrict__ depths,
                            const float* __restrict__ Kmat,
                            const float* __restrict__ Tmat,
                            int* __restrict__ binidx,
                            int* __restrict__ cnt) {
    const int n = blockIdx.y;                            // (b*T+t)*C + c
    const int p = blockIdx.x * blockDim.x + threadIdx.x; // 0..P-1
    const int v = p / Wp, u = p % Wp;

    const float* Kp = Kmat + n * 9;
    const float* M  = Tmat + n * 16;

    const float Sx = (float)Wp / (float)W;  // 0.125
    const float Sy = (float)Hp / (float)H;  // 0.125
    const float fx = Kp[0] * Sx, cx = Kp[2] * Sx;
    const float fy = Kp[4] * Sy, cy = Kp[5] * Sy;

    // T_cam_from_ego is rigid (bottom row 0,0,0,1; R orthonormal):
    // inv = [R^T | -R^T t]; we need rows 0 and 1 of the inverse.
    const float r00 = M[0], r01 = M[1], r02 = M[2], t0 = M[3];
    const float r10 = M[4], r11 = M[5], r12 = M[6], t1 = M[7];
    const float r20 = M[8], r21 = M[9], r22 = M[10], t2 = M[11];
    const float ti0 = -(r00 * t0 + r10 * t1 + r20 * t2);
    const float ti1 = -(r01 * t0 + r11 * t1 + r21 * t2);

    // nearest-resize: iy = v * (H/Hp) = v*8, ix = u*8
    const float d = depths[(size_t)n * H * W + (size_t)(v * (H / Hp)) * W + u * (W / Wp)];

    const float xc = ((float)u - cx) / fx * d;
    const float yc = ((float)v - cy) / fy * d;
    const float x  = r00 * xc + r10 * yc + r20 * d + ti0;
    const float y  = r01 * xc + r11 * yc + r21 * d + ti1;

    const bool valid = (d > 0.f) && (x >= X_MIN) && (x < X_MAX) &&
                       (y >= Y_MIN) && (y < Y_MAX);
    int bin = -1;
    if (valid) {
        const float ixf = floorf((x - X_MIN) * 2.f);
        const float iyf = floorf((y - Y_MIN) * 2.f);
        const int ix = (int)fminf(fmaxf(ixf, 0.f), (float)(WB - 1));
        const int iy = (int)fminf(fmaxf(iyf, 0.f), (float)(HB - 1));
        bin = iy * WB + ix;
        atomicAdd(&cnt[n * NBIN + bin], 1);
    }
    binidx[n * P + p] = bin;
}

// ---------------------------------------------------------------------------
// Phase B: scatter-add features. One block per (n, cr): feats reads coalesced,
// binidx L2-resident across the 64 channel blocks.
// grid = NB*Cr = 1536, block = 256
// ---------------------------------------------------------------------------
__global__ void scatter_kernel(const float* __restrict__ feats,
                               const int* __restrict__ binidx,
                               float* __restrict__ num) {
    const int bid = blockIdx.x;
    const int n = bid >> 6, cr = bid & 63;
    const int bt = n / C;

    const float* f  = feats + ((size_t)n * Cr + cr) * P;
    const int*   bi = binidx + n * P;
    float* numbt = num + (size_t)bt * NBIN * Cr;

    for (int p = threadIdx.x; p < P; p += blockDim.x) {
        const int b = bi[p];
        if (b >= 0) atomicAdd(&numbt[(size_t)b * Cr + cr], f[p]);
    }
}

// ---------------------------------------------------------------------------
// Phase C: den = sum_c max(cnt_c,1); out[b,t,cr,bin] = num[b,t,bin,cr]/den
// grid = BT*NBIN/256 = 625, block = 256
// ---------------------------------------------------------------------------
__global__ void finalize_kernel(const float* __restrict__ num,
                                const int* __restrict__ cnt,
                                float* __restrict__ out) {
    const int g   = blockIdx.x * blockDim.x + threadIdx.x; // 0..BT*NBIN-1
    const int bt  = g / NBIN;
    const int bin = g % NBIN;

    float den = 0.f;
#pragma unroll
    for (int c = 0; c < C; ++c) {
        const int cc = cnt[(bt * C + c) * NBIN + bin];
        den += (float)(cc > 1 ? cc : 1);
    }
    const float rcp = 1.f / den;  // den >= C > 0 always

    const float* nb = num + ((size_t)bt * NBIN + bin) * Cr;
    float*       ob = out + (size_t)bt * Cr * NBIN + bin;
#pragma unroll
    for (int cr = 0; cr < Cr; ++cr) {
        ob[(size_t)cr * NBIN] = nb[cr] * rcp;
    }
}

extern "C" void kernel_launch(void* const* d_in, const int* in_sizes, int n_in,
                              void* d_out, int out_size, void* d_ws, size_t ws_size,
                              hipStream_t stream) {
    const float* feats  = (const float*)d_in[0];
    const float* depths = (const float*)d_in[1];
    const float* Kmat   = (const float*)d_in[2];
    const float* Tmat   = (const float*)d_in[3];

    float* num    = (float*)d_ws;
    int*   cnt    = (int*)((char*)d_ws + NUM_BYTES);
    int*   binidx = (int*)((char*)d_ws + NUM_BYTES + CNT_BYTES);

    // zero num + cnt (binidx is fully overwritten)
    hipMemsetAsync(d_ws, 0, NUM_BYTES + CNT_BYTES, stream);

    geom_kernel<<<dim3(P / 256, NB), 256, 0, stream>>>(depths, Kmat, Tmat, binidx, cnt);
    scatter_kernel<<<NB * Cr, 256, 0, stream>>>(feats, binidx, num);
    finalize_kernel<<<(BT * NBIN) / 256, 256, 0, stream>>>(num, cnt, (float*)d_out);
}

// Round 9
// 294.781 us; speedup vs baseline: 1.1165x; 1.1165x over previous
//
#include <hip/hip_runtime.h>

// Problem constants (fixed by setup_inputs)
constexpr int B  = 2, T = 2, C = 6, Cr = 64, Hp = 32, Wp = 88;
constexpr int H  = 256, W = 704;
constexpr int HB = 200, WB = 200;
constexpr int NB   = B * T * C;       // 24 camera-slices
constexpr int BT   = B * T;           // 4
constexpr int P    = Hp * Wp;         // 2816 points per slice (= 11*256)
constexpr int NBIN = HB * WB;         // 40000 bins

constexpr float X_MIN = -50.f, Y_MIN = -50.f;
// rx = ry = 0.5 -> multiply by 2.0 (exact)

// workspace layout: cnt [NB*NBIN] int | binidx [NB*P] int | rden [BT*NBIN] float
constexpr size_t CNT_ELEMS  = (size_t)NB * NBIN;   // 960,000
constexpr size_t BIDX_ELEMS = (size_t)NB * P;      //  67,584
constexpr size_t CNT_BYTES  = CNT_ELEMS * 4;
constexpr size_t BIDX_BYTES = BIDX_ELEMS * 4;

constexpr size_t OUT_ELEMS = (size_t)BT * Cr * NBIN;  // 10,240,000

// ---------------------------------------------------------------------------
// Phase A: per-point geometry -> bin index (or -1), per-camera bin counts
// grid = (P/256, NB), block = 256
// ---------------------------------------------------------------------------
__global__ void geom_kernel(const float* __restrict__ depths,
                            const float* __restrict__ Kmat,
                            const float* __restrict__ Tmat,
                            int* __restrict__ binidx,
                            int* __restrict__ cnt) {
    const int n = blockIdx.y;
    const int p = blockIdx.x * blockDim.x + threadIdx.x;
    const int v = p / Wp, u = p % Wp;

    const float* Kp = Kmat + n * 9;
    const float* M  = Tmat + n * 16;

    const float Sx = (float)Wp / (float)W;  // 0.125
    const float Sy = (float)Hp / (float)H;  // 0.125
    const float fx = Kp[0] * Sx, cx = Kp[2] * Sx;
    const float fy = Kp[4] * Sy, cy = Kp[5] * Sy;

    // rigid inverse: inv = [R^T | -R^T t], need rows 0,1
    const float r00 = M[0], t0 = M[3];
    const float r10 = M[4], t1 = M[7];
    const float r20 = M[8], t2 = M[11];
    const float r01 = M[1], r11 = M[5], r21 = M[9];
    const float ti0 = -(r00 * t0 + r10 * t1 + r20 * t2);
    const float ti1 = -(r01 * t0 + r11 * t1 + r21 * t2);

    const float d = depths[(size_t)n * H * W + (size_t)(v * (H / Hp)) * W + u * (W / Wp)];

    const float xc = ((float)u - cx) / fx * d;
    const float yc = ((float)v - cy) / fy * d;
    const float x  = r00 * xc + r10 * yc + r20 * d + ti0;
    const float y  = r01 * xc + r11 * yc + r21 * d + ti1;

    const bool valid = (d > 0.f) && (x >= X_MIN) && (x < -X_MIN) &&
                       (y >= Y_MIN) && (y < -Y_MIN);
    int bin = -1;
    if (valid) {
        const float ixf = floorf((x - X_MIN) * 2.f);
        const float iyf = floorf((y - Y_MIN) * 2.f);
        const int ix = (int)fminf(fmaxf(ixf, 0.f), (float)(WB - 1));
        const int iy = (int)fminf(fmaxf(iyf, 0.f), (float)(HB - 1));
        bin = iy * WB + ix;
        atomicAdd(&cnt[n * NBIN + bin], 1);
    }
    binidx[n * P + p] = bin;
}

// ---------------------------------------------------------------------------
// Phase B: rden[bt][bin] = 1 / sum_c max(cnt,1)
// grid = BT*NBIN/256 = 625, block = 256
// ---------------------------------------------------------------------------
__global__ void rden_kernel(const int* __restrict__ cnt,
                            float* __restrict__ rden) {
    const int g   = blockIdx.x * blockDim.x + threadIdx.x;
    const int bt  = g / NBIN;
    const int bin = g % NBIN;
    float den = 0.f;
#pragma unroll
    for (int c = 0; c < C; ++c) {
        const int cc = cnt[(bt * C + c) * NBIN + bin];
        den += (float)(cc > 1 ? cc : 1);
    }
    rden[g] = 1.f / den;
}

// ---------------------------------------------------------------------------
// Phase C: scatter-add features directly into out ([bt][cr][bin] layout).
// Block (py, n*64+cr): lanes = consecutive p -> nearby bins -> same-line
// atomic batching; different cr -> lines 160KB apart (no cross-block bounce).
// grid = (P/256 = 11, NB*Cr = 1536), block = 256
// ---------------------------------------------------------------------------
__global__ void scatter_kernel(const float* __restrict__ feats,
                               const int* __restrict__ binidx,
                               float* __restrict__ out) {
    const int bid = blockIdx.y;
    const int n = bid >> 6, cr = bid & 63;
    const int bt = n / C;
    const int p = blockIdx.x * blockDim.x + threadIdx.x;

    const int b = binidx[n * P + p];
    if (b >= 0) {
        const float f = feats[((size_t)(n * Cr + cr)) * P + p];
        atomicAdd(&out[((size_t)(bt * Cr + cr)) * NBIN + b], f);
    }
}

// ---------------------------------------------------------------------------
// Phase D: out *= rden (broadcast over cr), float4-vectorized, in place.
// grid = OUT_ELEMS/4/256 = 10000, block = 256
// ---------------------------------------------------------------------------
__global__ void finalize_kernel(float* __restrict__ out,
                                const float* __restrict__ rden) {
    const size_t e = ((size_t)blockIdx.x * blockDim.x + threadIdx.x) * 4;
    const int bt  = (int)(e / ((size_t)Cr * NBIN));
    const int bin = (int)(e % NBIN);            // NBIN % 4 == 0, e % 4 == 0

    const float4 r = *(const float4*)(rden + (size_t)bt * NBIN + bin);
    float4 o = *(float4*)(out + e);
    o.x *= r.x; o.y *= r.y; o.z *= r.z; o.w *= r.w;
    *(float4*)(out + e) = o;
}

extern "C" void kernel_launch(void* const* d_in, const int* in_sizes, int n_in,
                              void* d_out, int out_size, void* d_ws, size_t ws_size,
                              hipStream_t stream) {
    const float* feats  = (const float*)d_in[0];
    const float* depths = (const float*)d_in[1];
    const float* Kmat   = (const float*)d_in[2];
    const float* Tmat   = (const float*)d_in[3];

    int*   cnt    = (int*)d_ws;
    int*   binidx = (int*)((char*)d_ws + CNT_BYTES);
    float* rden   = (float*)((char*)d_ws + CNT_BYTES + BIDX_BYTES);
    float* out    = (float*)d_out;

    hipMemsetAsync(cnt, 0, CNT_BYTES, stream);              // zero counts
    hipMemsetAsync(d_out, 0, OUT_ELEMS * 4, stream);        // zero accumulator

    geom_kernel<<<dim3(P / 256, NB), 256, 0, stream>>>(depths, Kmat, Tmat, binidx, cnt);
    rden_kernel<<<(BT * NBIN) / 256, 256, 0, stream>>>(cnt, rden);
    scatter_kernel<<<dim3(P / 256, NB * Cr), 256, 0, stream>>>(feats, binidx, out);
    finalize_kernel<<<OUT_ELEMS / 4 / 256, 256, 0, stream>>>(out, rden);
}

// Round 11
// 162.862 us; speedup vs baseline: 2.0209x; 1.8100x over previous
//
#include <hip/hip_runtime.h>

// Problem constants (fixed by setup_inputs)
constexpr int B  = 2, T = 2, C = 6, Cr = 64, Hp = 32, Wp = 88;
constexpr int H  = 256, W = 704;
constexpr int HB = 200, WB = 200;
constexpr int NB   = B * T * C;       // 24 camera-slices
constexpr int BT   = B * T;           // 4
constexpr int P    = Hp * Wp;         // 2816 points per slice (= 44*64)
constexpr int NBIN = HB * WB;         // 40000 bins
constexpr int PTS_BT = C * P;         // 16896 points per (b,t)

constexpr float X_MIN = -50.f, Y_MIN = -50.f;

// bin tiling for LDS-privatized accumulation
constexpr int TB    = 128;                      // bins per tile
constexpr int TILES = (NBIN + TB - 1) / TB;     // 313 (last tile: 64 bins)

// workspace layout: cnt | binidx | rden | feats_t
constexpr size_t CNT_ELEMS  = (size_t)NB * NBIN;        // 960,000
constexpr size_t BIDX_ELEMS = (size_t)NB * P;           //  67,584
constexpr size_t RDEN_ELEMS = (size_t)BT * NBIN;        // 160,000
constexpr size_t FT_ELEMS   = (size_t)NB * P * Cr;      // 4,325,376
constexpr size_t CNT_BYTES  = CNT_ELEMS * 4;
constexpr size_t BIDX_BYTES = BIDX_ELEMS * 4;
constexpr size_t RDEN_BYTES = RDEN_ELEMS * 4;

// ---------------------------------------------------------------------------
// Phase A: per-point geometry -> bin index (or -1), per-camera bin counts
// grid = (P/256, NB), block = 256
// ---------------------------------------------------------------------------
__global__ void geom_kernel(const float* __restrict__ depths,
                            const float* __restrict__ Kmat,
                            const float* __restrict__ Tmat,
                            int* __restrict__ binidx,
                            int* __restrict__ cnt) {
    const int n = blockIdx.y;
    const int p = blockIdx.x * blockDim.x + threadIdx.x;
    const int v = p / Wp, u = p % Wp;

    const float* Kp = Kmat + n * 9;
    const float* M  = Tmat + n * 16;

    const float Sx = (float)Wp / (float)W;  // 0.125
    const float Sy = (float)Hp / (float)H;  // 0.125
    const float fx = Kp[0] * Sx, cx = Kp[2] * Sx;
    const float fy = Kp[4] * Sy, cy = Kp[5] * Sy;

    // rigid inverse: inv = [R^T | -R^T t], need rows 0,1
    const float r00 = M[0], t0 = M[3];
    const float r10 = M[4], t1 = M[7];
    const float r20 = M[8], t2 = M[11];
    const float r01 = M[1], r11 = M[5], r21 = M[9];
    const float ti0 = -(r00 * t0 + r10 * t1 + r20 * t2);
    const float ti1 = -(r01 * t0 + r11 * t1 + r21 * t2);

    const float d = depths[(size_t)n * H * W + (size_t)(v * (H / Hp)) * W + u * (W / Wp)];

    const float xc = ((float)u - cx) / fx * d;
    const float yc = ((float)v - cy) / fy * d;
    const float x  = r00 * xc + r10 * yc + r20 * d + ti0;
    const float y  = r01 * xc + r11 * yc + r21 * d + ti1;

    const bool valid = (d > 0.f) && (x >= X_MIN) && (x < -X_MIN) &&
                       (y >= Y_MIN) && (y < -Y_MIN);
    int bin = -1;
    if (valid) {
        const float ixf = floorf((x - X_MIN) * 2.f);
        const float iyf = floorf((y - Y_MIN) * 2.f);
        const int ix = (int)fminf(fmaxf(ixf, 0.f), (float)(WB - 1));
        const int iy = (int)fminf(fmaxf(iyf, 0.f), (float)(HB - 1));
        bin = iy * WB + ix;
        atomicAdd(&cnt[n * NBIN + bin], 1);
    }
    binidx[n * P + p] = bin;
}

// ---------------------------------------------------------------------------
// Phase B: rden[bt][bin] = 1 / sum_c max(cnt,1)
// grid = BT*NBIN/256 = 625, block = 256
// ---------------------------------------------------------------------------
__global__ void rden_kernel(const int* __restrict__ cnt,
                            float* __restrict__ rden) {
    const int g   = blockIdx.x * blockDim.x + threadIdx.x;
    const int bt  = g / NBIN;
    const int bin = g % NBIN;
    float den = 0.f;
#pragma unroll
    for (int c = 0; c < C; ++c) {
        const int cc = cnt[(bt * C + c) * NBIN + bin];
        den += (float)(cc > 1 ? cc : 1);
    }
    rden[g] = 1.f / den;
}

// ---------------------------------------------------------------------------
// Phase C: transpose feats [n][cr][p] -> feats_t [n][p][cr]
// grid = (P/64 = 44, NB), block = 256; 64x64 tile in LDS (padded)
// ---------------------------------------------------------------------------
__global__ void transpose_kernel(const float* __restrict__ feats,
                                 float* __restrict__ feats_t) {
    __shared__ float tile[64][65];
    const int n  = blockIdx.y;
    const int p0 = blockIdx.x * 64;
    const int tp = threadIdx.x & 63;   // lane: p-offset on read, cr on write
    const int tq = threadIdx.x >> 6;   // wave id 0..3

    const float* src = feats + (size_t)n * Cr * P + p0;   // [cr][p]
#pragma unroll
    for (int k = 0; k < 16; ++k) {
        const int cr = k * 4 + tq;
        tile[cr][tp] = src[(size_t)cr * P + tp];          // coalesced 256B
    }
    __syncthreads();
    float* dst = feats_t + ((size_t)n * P + p0) * Cr;     // [p][cr]
#pragma unroll
    for (int k = 0; k < 16; ++k) {
        const int p = k * 4 + tq;
        dst[(size_t)p * Cr + tp] = tile[tp][p];           // coalesced 256B
    }
}

// ---------------------------------------------------------------------------
// Phase D: LDS-privatized accumulation + fused finalize.
// One block per (bin-tile, bt). acc[TB][64] f32 in LDS (32KB), XOR-swizzled:
//   slot(bin,cr) = bin*64 + (cr ^ (bin & 31))
//   - scatter: 64 lanes, same bin, cr=lane -> 32 banks x2 = conflict-free
//   - epilogue: lanes vary bin, cr fixed  -> 32 banks x2 = conflict-free
// Waves ballot-scan binidx; each match = one coalesced 256B feats_t read +
// one conflict-free LDS float atomicAdd per lane. Zero global float atomics.
// grid = (TILES = 313, BT = 4), block = 256
// ---------------------------------------------------------------------------
__global__ void accum_kernel(const float* __restrict__ feats_t,
                             const int* __restrict__ binidx,
                             const float* __restrict__ rden,
                             float* __restrict__ out) {
    __shared__ float acc[TB * 64];
    const int bt = blockIdx.y;
    const int lo = blockIdx.x * TB;

    for (int i = threadIdx.x; i < TB * 64; i += 256) acc[i] = 0.f;
    __syncthreads();

    const int lane = threadIdx.x & 63;
    const int wave = threadIdx.x >> 6;
    const int* bi      = binidx + (size_t)bt * PTS_BT;
    const float* ft    = feats_t + (size_t)bt * PTS_BT * Cr;

    // each wave scans PTS_BT/4 = 4224 points (= 66 * 64)
    const int seg = PTS_BT / 4;
    for (int base = wave * seg; base < (wave + 1) * seg; base += 64) {
        const int b = bi[base + lane];
        const bool match = (b >= lo) && (b < lo + TB);
        unsigned long long mask = __ballot(match);
        while (mask) {
            const int bit = __ffsll(mask) - 1;
            mask &= mask - 1;
            const int bm = __shfl(b, bit);                 // wave-uniform bin
            const int im = base + bit;                     // matching point
            const float v = ft[(size_t)im * Cr + lane];    // coalesced 256B
            atomicAdd(&acc[(bm - lo) * 64 + (lane ^ (bm & 31))], v);
        }
    }
    __syncthreads();

    // epilogue: thread t -> bin_local = t&127, cr range = (t>>7)*32 .. +32
    const int bl  = threadIdx.x & (TB - 1);
    const int bin = lo + bl;
    if (bin < NBIN) {
        const float r = rden[(size_t)bt * NBIN + bin];
        const int cr0 = (threadIdx.x >> 7) * 32;
        float* ob = out + (size_t)bt * Cr * NBIN + bin;
#pragma unroll
        for (int k = 0; k < 32; ++k) {
            const int cr = cr0 + k;
            ob[(size_t)cr * NBIN] = acc[bl * 64 + (cr ^ (bl & 31))] * r;
        }
    }
}

extern "C" void kernel_launch(void* const* d_in, const int* in_sizes, int n_in,
                              void* d_out, int out_size, void* d_ws, size_t ws_size,
                              hipStream_t stream) {
    const float* feats  = (const float*)d_in[0];
    const float* depths = (const float*)d_in[1];
    const float* Kmat   = (const float*)d_in[2];
    const float* Tmat   = (const float*)d_in[3];

    int*   cnt     = (int*)d_ws;
    int*   binidx  = (int*)((char*)d_ws + CNT_BYTES);
    float* rden    = (float*)((char*)d_ws + CNT_BYTES + BIDX_BYTES);
    float* feats_t = (float*)((char*)d_ws + CNT_BYTES + BIDX_BYTES + RDEN_BYTES);
    float* out     = (float*)d_out;

    hipMemsetAsync(cnt, 0, CNT_BYTES, stream);   // only cnt needs zeroing

    geom_kernel<<<dim3(P / 256, NB), 256, 0, stream>>>(depths, Kmat, Tmat, binidx, cnt);
    rden_kernel<<<(BT * NBIN) / 256, 256, 0, stream>>>(cnt, rden);
    transpose_kernel<<<dim3(P / 64, NB), 256, 0, stream>>>(feats, feats_t);
    accum_kernel<<<dim3(TILES, BT), 256, 0, stream>>>(feats_t, binidx, rden, out);
}